// Round 12
// baseline (408.616 us; speedup 1.0000x reference)
//
#include <hip/hip_runtime.h>
#include <hip/hip_bf16.h>

// NeuronGAT forward. Round 11:
//  - attn_mfma: register software-pipeline (prefetch next iter's K/V frags
//    during compute) + NCHUNK 8->16 (4->8 blocks/CU). Counters r9: MfmaUtil 16,
//    VALUBusy 56, Occ 28 -> ~25% stall on unpipelined L2 loads.
//  - pacc (16.78MB @ NCHUNK=16) exactly overlays hwres (dead after qkv_prep).
//  - everything else unchanged from r10.

#define NEG 0.2f
#define LOG2E 1.4426950408889634f

__device__ __forceinline__ float leaky(float v) { return v > 0.f ? v : NEG * v; }

__device__ __forceinline__ unsigned bf16u(float x) {
    unsigned u = __float_as_uint(x);
    u += 0x7FFFu + ((u >> 16) & 1u);
    return u >> 16;
}
__device__ __forceinline__ unsigned fmap(float f) {
    unsigned u = __float_as_uint(f);
    return (u & 0x80000000u) ? ~u : (u | 0x80000000u);
}
__device__ __forceinline__ float funmap(unsigned u) {
    unsigned b = (u & 0x80000000u) ? (u & 0x7FFFFFFFu) : ~u;
    return __uint_as_float(b);
}
__device__ __forceinline__ float fexp2(float x) {
#if __has_builtin(__builtin_amdgcn_exp2f)
    return __builtin_amdgcn_exp2f(x);
#else
    return exp2f(x);
#endif
}
__device__ __forceinline__ unsigned cvtpk(float lo, float hi) {
    unsigned r;
    asm("v_cvt_pk_bf16_f32 %0, %1, %2" : "=v"(r) : "v"(lo), "v"(hi));
    return r;
}

typedef __attribute__((ext_vector_type(8))) short bf16x8;
typedef __attribute__((ext_vector_type(16))) float f32x16;
typedef __attribute__((ext_vector_type(4))) unsigned uint4v;

__device__ __forceinline__ void split1(float v, unsigned& hb, unsigned& lb) {
    hb = bf16u(v);
    float hf = __uint_as_float(hb << 16);
    lb = bf16u(v - hf);
}

__global__ void split_rows(const float* __restrict__ in,
                           unsigned short* __restrict__ hi,
                           unsigned short* __restrict__ lo, int total4)
{
    int i = blockIdx.x * 256 + threadIdx.x;
    if (i >= total4) return;
    float4 v = ((const float4*)in)[i];
    float vv[4] = {v.x, v.y, v.z, v.w};
    ushort4 h, l;
#pragma unroll
    for (int j = 0; j < 4; ++j) {
        unsigned hb, lb;
        split1(vv[j], hb, lb);
        (&h.x)[j] = (unsigned short)hb;
        (&l.x)[j] = (unsigned short)lb;
    }
    ((ushort4*)hi)[i] = h;
    ((ushort4*)lo)[i] = l;
}

struct WEnt { const float* src; unsigned short* hi; unsigned short* lo; int K; int N; };
struct WArr { WEnt e[15]; };

__global__ void split_weights(WArr a)
{
    WEnt w = a.e[blockIdx.y];
    int id = blockIdx.x * 256 + threadIdx.x;
    if (id >= w.K * w.N) return;
    int k = id / w.N, n = id - k * w.N;
    unsigned hb, lb;
    split1(w.src[id], hb, lb);
    w.hi[(size_t)n * w.K + k] = (unsigned short)hb;
    w.lo[(size_t)n * w.K + k] = (unsigned short)lb;
}

// ------------------------------------------------- MFMA split-bf16 GEMM
__global__ __launch_bounds__(256) void gemm_mfma(
    const unsigned short* __restrict__ Ahi, const unsigned short* __restrict__ Alo,
    const unsigned short* __restrict__ Bhi, const unsigned short* __restrict__ Blo,
    const float* __restrict__ bias, float* __restrict__ C,
    unsigned short* __restrict__ Chi, unsigned short* __restrict__ Clo,
    const float* __restrict__ jkB, const float* __restrict__ jkC,
    unsigned* __restrict__ kmaxDst, const float* __restrict__ kbias,
    int M, int N, int K, int act)
{
    const int lane = threadIdx.x & 63, wid = threadIdx.x >> 6;
    const int hb4 = lane >> 5, lq = lane & 31;
    const int row0 = blockIdx.y * 64 + (wid >> 1) * 32;
    const int col0 = blockIdx.x * 64 + (wid & 1) * 32;
    const size_t abase = (size_t)(row0 + lq) * K + hb4 * 8;
    const size_t bbase = (size_t)(col0 + lq) * K + hb4 * 8;
    f32x16 acc0, acc1;
#pragma unroll
    for (int r = 0; r < 16; ++r) { acc0[r] = 0.f; acc1[r] = 0.f; }
    for (int k0 = 0; k0 < K; k0 += 16) {
        bf16x8 a_h = *(const bf16x8*)(Ahi + abase + k0);
        bf16x8 a_l = *(const bf16x8*)(Alo + abase + k0);
        bf16x8 b_h = *(const bf16x8*)(Bhi + bbase + k0);
        bf16x8 b_l = *(const bf16x8*)(Blo + bbase + k0);
        acc0 = __builtin_amdgcn_mfma_f32_32x32x16_bf16(a_h, b_h, acc0, 0, 0, 0);
        acc1 = __builtin_amdgcn_mfma_f32_32x32x16_bf16(a_l, b_h, acc1, 0, 0, 0);
        acc1 = __builtin_amdgcn_mfma_f32_32x32x16_bf16(a_h, b_l, acc1, 0, 0, 0);
    }
    int col = col0 + lq;
    if (col >= N) return;
    float bs = bias ? bias[col] : 0.f;
    float kmx = 0.f;
#pragma unroll
    for (int r = 0; r < 16; ++r) {
        int row = row0 + (r & 3) + 8 * (r >> 2) + 4 * hb4;
        float v = acc0[r] + acc1[r] + bs;
        if (act) v = leaky(v);
        if (jkB) v = fmaxf(fmaxf(v, jkB[(size_t)row * N + col]),
                           jkC[(size_t)row * N + col]);
        if (kmaxDst) kmx = fmaxf(kmx, fabsf(v + kbias[col & 63]));
        if (C) C[(size_t)row * N + col] = v;
        if (Chi) {
            unsigned hh, ll;
            split1(v, hh, ll);
            Chi[(size_t)row * N + col] = (unsigned short)hh;
            Clo[(size_t)row * N + col] = (unsigned short)ll;
        }
    }
    if (kmaxDst && col >= 64 && col < 128)
        atomicMax(&kmaxDst[col - 64], __float_as_uint(kmx));
}

// ---------------------------------- GAT scores (x log2e) + global head max
template <int H>
__global__ __launch_bounds__(256) void sd_kernel(
    const float* __restrict__ hwres, int S,
    const float* __restrict__ a_s, const float* __restrict__ a_d,
    float* __restrict__ sval, float* __restrict__ dval,
    unsigned* __restrict__ svmax, int Nn)
{
    int i = blockIdx.x * 256 + threadIdx.x;
    int n = i / H, h = i & (H - 1);
    const float4* row = (const float4*)(hwres + (size_t)n * S + h * 64);
    const float4* as4 = (const float4*)(a_s + h * 64);
    const float4* ad4 = (const float4*)(a_d + h * 64);
    float s = 0.f, d = 0.f;
#pragma unroll
    for (int c = 0; c < 16; ++c) {
        float4 x = row[c], a = as4[c], b = ad4[c];
        s += x.x * a.x + x.y * a.y + x.z * a.z + x.w * a.w;
        d += x.x * b.x + x.y * b.y + x.z * b.z + x.w * b.w;
    }
    s *= LOG2E;
    d *= LOG2E;
    sval[i] = s;
    dval[i] = d;
    float m = s;
#pragma unroll
    for (int off = H; off < 64; off <<= 1) m = fmaxf(m, __shfl_xor(m, off));
    if ((threadIdx.x & 63) < H) atomicMax(&svmax[h], fmap(m));
}

// ------------------------------------------------- CSR build (by dst)
__global__ void csr_count(const int* __restrict__ ei, int* __restrict__ cnt, int E) {
    int i = blockIdx.x * 256 + threadIdx.x;
    if (i < E) atomicAdd(&cnt[ei[E + i]], 1);
}

__global__ __launch_bounds__(256) void csr_scan(const int* __restrict__ cnt,
                                                int* __restrict__ rowptr,
                                                int* __restrict__ fill, int Nn)
{
    __shared__ int part[256];
    int t = threadIdx.x;
    int loc[32];
    int s = 0;
#pragma unroll
    for (int j = 0; j < 32; ++j) { loc[j] = s; s += cnt[t * 32 + j]; }
    part[t] = s;
    __syncthreads();
    for (int d = 1; d < 256; d <<= 1) {
        int v = (t >= d) ? part[t - d] : 0;
        __syncthreads();
        part[t] += v;
        __syncthreads();
    }
    int off = (t > 0) ? part[t - 1] : 0;
#pragma unroll
    for (int j = 0; j < 32; ++j) {
        int v = off + loc[j];
        rowptr[t * 32 + j] = v;
        fill[t * 32 + j] = v;
    }
    if (t == 255) rowptr[Nn] = part[255];
}

__global__ void csr_scatter(const int* __restrict__ ei, int* __restrict__ fill,
                            int* __restrict__ srcidx, int E) {
    int i = blockIdx.x * 256 + threadIdx.x;
    if (i < E) {
        int d = ei[E + i];
        int p = atomicAdd(&fill[d], 1);
        srcidx[p] = ei[i];
    }
}

// ------------------- single-pass GAT gather (fixed-bound, exp2 domain)
__global__ __launch_bounds__(256) void gat_gather4(
    const int* __restrict__ rowptr, const int* __restrict__ srcidx,
    const float* __restrict__ hwres, int S,
    const float* __restrict__ sval, const float* __restrict__ dval,
    const unsigned* __restrict__ svmax, float* __restrict__ gout, int Nn)
{
    const int node = blockIdx.x * 4 + (threadIdx.x >> 6);
    const int lane = threadIdx.x & 63;
    const int hd = lane >> 4;
    const int cb = lane * 4;
    const int beg = rowptr[node], end = rowptr[node + 1];
    const float dv = dval[node * 4 + hd];
    const float B = leaky(funmap(svmax[hd]) + dv);
    float p = fexp2(leaky(sval[node * 4 + hd] + dv) - B);
    float l = p;
    float4 hv = *(const float4*)(hwres + (size_t)node * S + cb);
    float a0 = p * hv.x, a1 = p * hv.y, a2 = p * hv.z, a3 = p * hv.w;
    int i = beg;
    for (; i + 4 <= end; i += 4) {
        int s0 = srcidx[i], s1 = srcidx[i + 1];
        int s2 = srcidx[i + 2], s3 = srcidx[i + 3];
        float p0 = fexp2(leaky(sval[s0 * 4 + hd] + dv) - B);
        float p1 = fexp2(leaky(sval[s1 * 4 + hd] + dv) - B);
        float p2 = fexp2(leaky(sval[s2 * 4 + hd] + dv) - B);
        float p3 = fexp2(leaky(sval[s3 * 4 + hd] + dv) - B);
        float4 r0 = *(const float4*)(hwres + (size_t)s0 * S + cb);
        float4 r1 = *(const float4*)(hwres + (size_t)s1 * S + cb);
        float4 r2 = *(const float4*)(hwres + (size_t)s2 * S + cb);
        float4 r3 = *(const float4*)(hwres + (size_t)s3 * S + cb);
        l += (p0 + p1) + (p2 + p3);
        a0 += p0 * r0.x + p1 * r1.x + p2 * r2.x + p3 * r3.x;
        a1 += p0 * r0.y + p1 * r1.y + p2 * r2.y + p3 * r3.y;
        a2 += p0 * r0.z + p1 * r1.z + p2 * r2.z + p3 * r3.z;
        a3 += p0 * r0.w + p1 * r1.w + p2 * r2.w + p3 * r3.w;
    }
    for (; i < end; ++i) {
        int s0 = srcidx[i];
        float p0 = fexp2(leaky(sval[s0 * 4 + hd] + dv) - B);
        float4 r0 = *(const float4*)(hwres + (size_t)s0 * S + cb);
        l += p0;
        a0 += p0 * r0.x; a1 += p0 * r0.y; a2 += p0 * r0.z; a3 += p0 * r0.w;
    }
    float inv = 1.f / l;
    *(float4*)(gout + (size_t)node * 256 + cb) =
        make_float4(a0 * inv, a1 * inv, a2 * inv, a3 * inv);
}

__global__ __launch_bounds__(256) void gat_gather1(
    const int* __restrict__ rowptr, const int* __restrict__ srcidx,
    const float* __restrict__ hwres, int S,
    const float* __restrict__ sval, const float* __restrict__ dval,
    const unsigned* __restrict__ svmax, float* __restrict__ gout, int Nn)
{
    const int node = blockIdx.x * 4 + (threadIdx.x >> 6);
    const int lane = threadIdx.x & 63;
    const int beg = rowptr[node], end = rowptr[node + 1];
    const float dv = dval[node];
    const float B = leaky(funmap(svmax[0]) + dv);
    float p = fexp2(leaky(sval[node] + dv) - B);
    float l = p;
    float acc = p * hwres[(size_t)node * S + lane];
    int i = beg;
    for (; i + 4 <= end; i += 4) {
        int s0 = srcidx[i], s1 = srcidx[i + 1];
        int s2 = srcidx[i + 2], s3 = srcidx[i + 3];
        float p0 = fexp2(leaky(sval[s0] + dv) - B);
        float p1 = fexp2(leaky(sval[s1] + dv) - B);
        float p2 = fexp2(leaky(sval[s2] + dv) - B);
        float p3 = fexp2(leaky(sval[s3] + dv) - B);
        l += (p0 + p1) + (p2 + p3);
        acc += p0 * hwres[(size_t)s0 * S + lane] + p1 * hwres[(size_t)s1 * S + lane]
             + p2 * hwres[(size_t)s2 * S + lane] + p3 * hwres[(size_t)s3 * S + lane];
    }
    for (; i < end; ++i) {
        int s0 = srcidx[i];
        float p0 = fexp2(leaky(sval[s0] + dv) - B);
        l += p0;
        acc += p0 * hwres[(size_t)s0 * S + lane];
    }
    gout[(size_t)node * 64 + lane] = acc / l;
}

// ------------------------------------------------- BatchNorm
__global__ void bn_partial(const float* __restrict__ gout, double* __restrict__ sums,
                           int Nn, int C)
{
    int t = threadIdx.x;
    int c = t % C, sub = t / C, nsub = blockDim.x / C;
    int rbase = blockIdx.x * 32;
    double s = 0.0, sq = 0.0;
    for (int r = rbase + sub; r < rbase + 32; r += nsub) {
        float x = gout[(size_t)r * C + c];
        s += x;
        sq += (double)x * x;
    }
    atomicAdd(&sums[c], s);
    atomicAdd(&sums[C + c], sq);
}

__global__ void bn_res_act(const float* __restrict__ gout,
                           const float* __restrict__ hwres, int S, int logC,
                           const double* __restrict__ bnsum, double invN,
                           const float* __restrict__ g, const float* __restrict__ be,
                           float* __restrict__ outp,
                           unsigned short* __restrict__ shi,
                           unsigned short* __restrict__ slo, int total)
{
    int i = blockIdx.x * blockDim.x + threadIdx.x;
    if (i >= total) return;
    int C = 1 << logC;
    int c = i & (C - 1), row = i >> logC;
    double m = bnsum[c] * invN;
    double var = bnsum[C + c] * invN - m * m;
    float mu = (float)m;
    float rstd = (float)(1.0 / sqrt(var + 1e-5));
    float v = (gout[i] - mu) * rstd * g[c] + be[c]
              + hwres[(size_t)row * S + C + c];
    v = leaky(v);
    if (outp) outp[i] = v;
    if (shi) {
        unsigned hb, lb;
        split1(v, hb, lb);
        shi[i] = (unsigned short)hb;
        slo[i] = (unsigned short)lb;
    }
}

// ---------------- merged attn prep: Qb/Kb (exp2-scaled) + bound + sigma-V
__global__ void qkv_prep(const float* __restrict__ zqkv,
                         const float* __restrict__ qb, const float* __restrict__ kb,
                         const float* __restrict__ vb,
                         const unsigned* __restrict__ kmaxu,
                         __hip_bfloat16* __restrict__ Qb, __hip_bfloat16* __restrict__ Kb,
                         __hip_bfloat16* __restrict__ Vf, float* __restrict__ bound,
                         int N)
{
    int idx = blockIdx.x * 256 + threadIdx.x;
    if (idx < 2 * N) {
        int h = idx / N, row = idx - h * N;
        const float scale = 0.17677669529663687f * LOG2E;
        const float* qp = zqkv + (size_t)row * 192 + h * 32;
        const float* kp = zqkv + (size_t)row * 192 + 64 + h * 32;
        float b = 0.f;
        unsigned qo[16], ko[16];
#pragma unroll
        for (int i = 0; i < 16; ++i) {
            float q0 = (qp[2 * i] + qb[h * 32 + 2 * i]) * scale;
            float q1 = (qp[2 * i + 1] + qb[h * 32 + 2 * i + 1]) * scale;
            float k0 = kp[2 * i] + kb[h * 32 + 2 * i];
            float k1 = kp[2 * i + 1] + kb[h * 32 + 2 * i + 1];
            b += fabsf(q0) * __uint_as_float(kmaxu[h * 32 + 2 * i]);
            b += fabsf(q1) * __uint_as_float(kmaxu[h * 32 + 2 * i + 1]);
            qo[i] = bf16u(q0) | (bf16u(q1) << 16);
            ko[i] = bf16u(k0) | (bf16u(k1) << 16);
        }
        uint4* qd = (uint4*)(Qb + (size_t)idx * 32);
        uint4* kd = (uint4*)(Kb + (size_t)idx * 32);
#pragma unroll
        for (int i = 0; i < 4; ++i) {
            qd[i] = make_uint4(qo[4 * i], qo[4 * i + 1], qo[4 * i + 2], qo[4 * i + 3]);
            kd[i] = make_uint4(ko[4 * i], ko[4 * i + 1], ko[4 * i + 2], ko[4 * i + 3]);
        }
        bound[idx] = b;
    } else {
        int j = idx - 2 * N;
        if (j >= 2 * (N >> 4) * 64) return;
        int lane = j & 63;
        int g = (j >> 6) % (N >> 4);
        int h = (j >> 6) / (N >> 4);
        int hi = lane >> 5;
        int kbase = g * 16 + 4 * hi;
        int d = (lane & 31) + h * 32;
        float bd = vb[d];
        unsigned o[4];
#pragma unroll
        for (int i = 0; i < 4; ++i) {
            int r0 = kbase + ((2 * i) & 3) + 8 * (i >> 1);
            unsigned u0 = bf16u(zqkv[(size_t)r0 * 192 + 128 + d] + bd);
            unsigned u1 = bf16u(zqkv[(size_t)(r0 + 1) * 192 + 128 + d] + bd);
            o[i] = u0 | (u1 << 16);
        }
        *(uint4*)(Vf + (size_t)j * 8) = make_uint4(o[0], o[1], o[2], o[3]);
    }
}

// ------------------------------------------------- MFMA self-attention
// sigma-permuted V; register software-pipeline on K/V frag loads.
__global__ __launch_bounds__(256) void attn_mfma(
    const __hip_bfloat16* __restrict__ Qb, const __hip_bfloat16* __restrict__ Kb,
    const __hip_bfloat16* __restrict__ Vf, const float* __restrict__ bound,
    float* __restrict__ pl, __hip_bfloat16* __restrict__ pacc,
    int N, int nchunk, int chunksz)
{
    const int lane = threadIdx.x & 63;
    const int wid = threadIdx.x >> 6;
    const int hi = lane >> 5, lq = lane & 31;
    const int chunk = blockIdx.x;
    const int qtile = blockIdx.y * 4 + wid;
    const int head = qtile / (N >> 5);
    const int q0 = (qtile % (N >> 5)) * 32;
    const int kbase = chunk * chunksz;
    const int kend = kbase + chunksz;

    const size_t qrow = (size_t)head * N + q0 + lq;
    const bf16x8 qf0 = *(const bf16x8*)(Qb + qrow * 32 + hi * 8);
    const bf16x8 qf1 = *(const bf16x8*)(Qb + qrow * 32 + hi * 8 + 16);
    const float bnd = bound[qrow];

    f32x16 oacc;
#pragma unroll
    for (int r = 0; r < 16; ++r) oacc[r] = 0.f;
    float lsum = 0.f;

    // prologue loads for first iter
    size_t krow = (size_t)head * N + kbase + lq;
    bf16x8 kf0 = *(const bf16x8*)(Kb + krow * 32 + hi * 8);
    bf16x8 kf1 = *(const bf16x8*)(Kb + krow * 32 + hi * 8 + 16);
    const __hip_bfloat16* vfb0 =
        Vf + (((size_t)head * (N >> 4) + (kbase >> 4)) * 64 + lane) * 8;
    bf16x8 vf0 = *(const bf16x8*)vfb0;
    bf16x8 vf1 = *(const bf16x8*)(vfb0 + 512);

    for (int kt = kbase; kt < kend; kt += 32) {
        // prefetch next iter's frags (overlaps with compute below)
        bf16x8 kf0n = kf0, kf1n = kf1, vf0n = vf0, vf1n = vf1;
        int ktn = kt + 32;
        if (ktn < kend) {
            size_t krn = (size_t)head * N + ktn + lq;
            kf0n = *(const bf16x8*)(Kb + krn * 32 + hi * 8);
            kf1n = *(const bf16x8*)(Kb + krn * 32 + hi * 8 + 16);
            const __hip_bfloat16* vfn =
                Vf + (((size_t)head * (N >> 4) + (ktn >> 4)) * 64 + lane) * 8;
            vf0n = *(const bf16x8*)vfn;
            vf1n = *(const bf16x8*)(vfn + 512);
        }

        f32x16 s;
#pragma unroll
        for (int r = 0; r < 16; ++r) s[r] = 0.f;
        s = __builtin_amdgcn_mfma_f32_32x32x16_bf16(kf0, qf0, s, 0, 0, 0);
        s = __builtin_amdgcn_mfma_f32_32x32x16_bf16(kf1, qf1, s, 0, 0, 0);

        float p[16];
#pragma unroll
        for (int r = 0; r < 16; ++r) p[r] = fexp2(s[r] - bnd);
        float ls = 0.f;
#pragma unroll
        for (int r = 0; r < 16; ++r) ls += p[r];
        lsum += ls;

        uint4v b1, b2;
        b1[0] = cvtpk(p[0], p[1]);
        b1[1] = cvtpk(p[2], p[3]);
        b1[2] = cvtpk(p[4], p[5]);
        b1[3] = cvtpk(p[6], p[7]);
        b2[0] = cvtpk(p[8], p[9]);
        b2[1] = cvtpk(p[10], p[11]);
        b2[2] = cvtpk(p[12], p[13]);
        b2[3] = cvtpk(p[14], p[15]);
        oacc = __builtin_amdgcn_mfma_f32_32x32x16_bf16(
            vf0, __builtin_bit_cast(bf16x8, b1), oacc, 0, 0, 0);
        oacc = __builtin_amdgcn_mfma_f32_32x32x16_bf16(
            vf1, __builtin_bit_cast(bf16x8, b2), oacc, 0, 0, 0);

        kf0 = kf0n; kf1 = kf1n; vf0 = vf0n; vf1 = vf1n;
    }
    lsum += __shfl_xor(lsum, 32);
    const size_t hr = (size_t)head * N + q0 + lq;
    if (hi == 0) pl[hr * nchunk + chunk] = lsum;
    __hip_bfloat16* pb = pacc + (hr * nchunk + chunk) * 32;
#pragma unroll
    for (int rg = 0; rg < 4; ++rg) {
        unsigned lo = cvtpk(oacc[rg * 4 + 0], oacc[rg * 4 + 1]);
        unsigned hw2 = cvtpk(oacc[rg * 4 + 2], oacc[rg * 4 + 3]);
        *(uint2*)(pb + rg * 8 + hi * 4) = make_uint2(lo, hw2);
    }
}

// combine -> split only (fp32 ao never consumed)
__global__ void attn_combine(const float* __restrict__ pl,
                             const __hip_bfloat16* __restrict__ pacc,
                             unsigned short* __restrict__ shi,
                             unsigned short* __restrict__ slo, int N, int nchunk)
{
    int i = blockIdx.x * blockDim.x + threadIdx.x;
    if (i >= 2 * N * 32) return;
    int hr = i >> 5, cc = i & 31;
    float l = 0.f, a = 0.f;
    for (int c = 0; c < nchunk; ++c) {
        l += pl[(size_t)hr * nchunk + c];
        a += __bfloat162float(pacc[((size_t)hr * nchunk + c) * 32 + cc]);
    }
    int head = hr / N, row = hr - head * N;
    float v = a / l;
    size_t oi = (size_t)row * 64 + head * 32 + cc;
    unsigned hb, lb;
    split1(v, hb, lb);
    shi[oi] = (unsigned short)hb;
    slo[oi] = (unsigned short)lb;
}

// ----------------------------------------------------------------- host
extern "C" void kernel_launch(void* const* d_in, const int* in_sizes, int n_in,
                              void* d_out, int out_size, void* d_ws, size_t ws_size,
                              hipStream_t stream)
{
    const float* x = (const float*)d_in[0];
    const int* ei = (const int*)d_in[1];
    const float* w[3]   = {(const float*)d_in[2], (const float*)d_in[6],  (const float*)d_in[10]};
    const float* as_[3] = {(const float*)d_in[3], (const float*)d_in[7],  (const float*)d_in[11]};
    const float* ad_[3] = {(const float*)d_in[4], (const float*)d_in[8],  (const float*)d_in[12]};
    const float* rw[3]  = {(const float*)d_in[5], (const float*)d_in[9],  (const float*)d_in[13]};
    const float* p0 = (const float*)d_in[14];
    const float* p1 = (const float*)d_in[15];
    const float* qw = (const float*)d_in[16];
    const float* kw = (const float*)d_in[17];
    const float* vw = (const float*)d_in[18];
    const float* ow = (const float*)d_in[19];
    const float* m1w = (const float*)d_in[20];
    const float* m2w = (const float*)d_in[21];
    const float* m3w = (const float*)d_in[22];
    const float* g_[3]  = {(const float*)d_in[23], (const float*)d_in[24], (const float*)d_in[25]};
    const float* be_[3] = {(const float*)d_in[26], (const float*)d_in[27], (const float*)d_in[28]};
    const float* qb  = (const float*)d_in[32];
    const float* kb  = (const float*)d_in[33];
    const float* vb  = (const float*)d_in[34];
    const float* ob  = (const float*)d_in[35];
    const float* m1b = (const float*)d_in[36];
    const float* m2b = (const float*)d_in[37];
    const float* m3b = (const float*)d_in[38];

    const int N = in_sizes[0] / 64; // 8192
    const int E = in_sizes[1] / 2;  // 262144

    float* ws = (float*)d_ws;
    size_t off = 0;
    auto alloc = [&](size_t n) {
        float* p = ws + off;
        off += (n + 255) & ~(size_t)255;
        return p;
    };
    float* hwres = alloc((size_t)N * 512);
    float* gout  = alloc((size_t)N * 256);
    unsigned short* sChi = (unsigned short*)alloc((size_t)N * 128);
    unsigned short* sClo = (unsigned short*)alloc((size_t)N * 128);
    float* h2   = alloc((size_t)N * 64);
    float* sval = alloc((size_t)N * 4);
    float* dval = alloc((size_t)N * 4);
    size_t ms_begin = off;
    int* cnt = (int*)alloc(N);
    double* bnsum = (double*)alloc(3 * 1024);
    unsigned* kmaxu = (unsigned*)alloc(64);
    unsigned* svmax = (unsigned*)alloc(16);
    size_t ms_end = off;
    int* rowptr = (int*)alloc(N + 256);
    int* fill   = (int*)alloc(N);
    int* srcidx = (int*)alloc(E);
    unsigned short* sAhi = (unsigned short*)alloc((size_t)N * 128);
    unsigned short* sAlo = (unsigned short*)alloc((size_t)N * 128);
    unsigned short* sBhi = (unsigned short*)alloc((size_t)N * 32);
    unsigned short* sBlo = (unsigned short*)alloc((size_t)N * 32);
    unsigned short* G0h = (unsigned short*)alloc(512 * 64 / 2);
    unsigned short* G0l = (unsigned short*)alloc(512 * 64 / 2);
    unsigned short* G1h = (unsigned short*)alloc(512 * 256 / 2);
    unsigned short* G1l = (unsigned short*)alloc(512 * 256 / 2);
    unsigned short* G2h = (unsigned short*)alloc(128 * 256 / 2);
    unsigned short* G2l = (unsigned short*)alloc(128 * 256 / 2);
    unsigned short* P0h = (unsigned short*)alloc(64 * 256 / 2);
    unsigned short* P0l = (unsigned short*)alloc(64 * 256 / 2);
    unsigned short* P1h = (unsigned short*)alloc(64 * 256 / 2);
    unsigned short* P1l = (unsigned short*)alloc(64 * 256 / 2);
    unsigned short* Gqh = (unsigned short*)alloc(192 * 64 / 2);
    unsigned short* Gql = (unsigned short*)alloc(192 * 64 / 2);
    unsigned short* Owh = (unsigned short*)alloc(64 * 64 / 2);
    unsigned short* Owl = (unsigned short*)alloc(64 * 64 / 2);
    unsigned short* M1h = (unsigned short*)alloc(64 * 64 / 2);
    unsigned short* M1l = (unsigned short*)alloc(64 * 64 / 2);
    unsigned short* M2h = (unsigned short*)alloc(64 * 64 / 2);
    unsigned short* M2l = (unsigned short*)alloc(64 * 64 / 2);
    unsigned short* M3h = (unsigned short*)alloc(64 * 32 / 2);
    unsigned short* M3l = (unsigned short*)alloc(64 * 32 / 2);
    float* zqkv = hwres;
    // NCHUNK=16: pacc (2N*16*32 bf16 = 16.78MB) overlays hwres EXACTLY
    // (N*512 floats); zqkv is dead once qkv_prep has run.
    const int NCHUNK = 16;
    __hip_bfloat16* pacc = (__hip_bfloat16*)hwres;
    float* tA = gout;
    float* tB = gout + (size_t)N * 64;
    __hip_bfloat16* Qb = (__hip_bfloat16*)sChi;
    __hip_bfloat16* Kb = Qb + (size_t)2 * N * 32;
    __hip_bfloat16* Vf = Kb + (size_t)2 * N * 32;
    float* boundArr = (float*)(Vf + (size_t)2 * N * 32);
    float* pl = h2;

    {
        WArr wa;
        wa.e[0]  = WEnt{w[0],  G0h,              G0l,              64, 256};
        wa.e[1]  = WEnt{rw[0], G0h + 256 * 64,   G0l + 256 * 64,   64, 256};
        wa.e[2]  = WEnt{w[1],  G1h,              G1l,              256, 256};
        wa.e[3]  = WEnt{rw[1], G1h + 256 * 256,  G1l + 256 * 256,  256, 256};
        wa.e[4]  = WEnt{w[2],  G2h,              G2l,              256, 64};
        wa.e[5]  = WEnt{rw[2], G2h + 64 * 256,   G2l + 64 * 256,   256, 64};
        wa.e[6]  = WEnt{p0,    P0h,              P0l,              256, 64};
        wa.e[7]  = WEnt{p1,    P1h,              P1l,              256, 64};
        wa.e[8]  = WEnt{qw,    Gqh,              Gql,              64, 64};
        wa.e[9]  = WEnt{kw,    Gqh + 64 * 64,    Gql + 64 * 64,    64, 64};
        wa.e[10] = WEnt{vw,    Gqh + 128 * 64,   Gql + 128 * 64,   64, 64};
        wa.e[11] = WEnt{ow,    Owh,              Owl,              64, 64};
        wa.e[12] = WEnt{m1w,   M1h,              M1l,              64, 64};
        wa.e[13] = WEnt{m2w,   M2h,              M2l,              64, 32};
        wa.e[14] = WEnt{m3w,   M3h,              M3l,              32, 10};
        split_weights<<<dim3(256, 15), 256, 0, stream>>>(wa);
    }
    hipMemsetAsync(ws + ms_begin, 0, (ms_end - ms_begin) * 4, stream);
    csr_count<<<(E + 255) / 256, 256, 0, stream>>>(ei, cnt, E);
    csr_scan<<<1, 256, 0, stream>>>(cnt, rowptr, fill, N);
    csr_scatter<<<(E + 255) / 256, 256, 0, stream>>>(ei, fill, srcidx, E);
    split_rows<<<(N * 64 / 4 + 255) / 256, 256, 0, stream>>>(x, sAhi, sAlo, N * 64 / 4);

    auto gemmM = [&](const unsigned short* Ah, const unsigned short* Al,
                     const unsigned short* Bh, const unsigned short* Bl,
                     const float* bias, float* C, unsigned short* Chi,
                     unsigned short* Clo, const float* jkB, const float* jkC,
                     unsigned* kmx, const float* kbias,
                     int M, int Nc, int K, int act) {
        dim3 grid((Nc + 63) / 64, M / 64);
        gemm_mfma<<<grid, 256, 0, stream>>>(Ah, Al, Bh, Bl, bias, C, Chi, Clo,
                                            jkB, jkC, kmx, kbias, M, Nc, K, act);
    };

    const unsigned short* inh[3] = {sAhi, sChi, sAhi};
    const unsigned short* inl[3] = {sAlo, sClo, sAlo};
    unsigned short* outh[3] = {sChi, sAhi, nullptr};
    unsigned short* outl[3] = {sClo, sAlo, nullptr};
    const unsigned short* Gh[3] = {G0h, G1h, G2h};
    const unsigned short* Gl[3] = {G0l, G1l, G2l};
    int Ksz[3] = {64, 256, 256}, Csz[3] = {256, 256, 64}, logC[3] = {8, 8, 6};
    int Hh[3] = {4, 4, 1};

    for (int l = 0; l < 3; ++l) {
        int C = Csz[l], S = 2 * C;
        gemmM(inh[l], inl[l], Gh[l], Gl[l], nullptr, hwres, nullptr, nullptr,
              nullptr, nullptr, nullptr, nullptr, N, S, Ksz[l], 0);
        if (Hh[l] == 4) {
            sd_kernel<4><<<N * 4 / 256, 256, 0, stream>>>(
                hwres, S, as_[l], ad_[l], sval, dval, svmax + l * 4, N);
            gat_gather4<<<N / 4, 256, 0, stream>>>(
                rowptr, srcidx, hwres, S, sval, dval, svmax + l * 4, gout, N);
        } else {
            sd_kernel<1><<<N / 256, 256, 0, stream>>>(
                hwres, S, as_[l], ad_[l], sval, dval, svmax + l * 4, N);
            gat_gather1<<<N / 4, 256, 0, stream>>>(
                rowptr, srcidx, hwres, S, sval, dval, svmax + l * 4, gout, N);
        }
        double* bns = bnsum + l * 512;
        bn_partial<<<N / 32, 256, 0, stream>>>(gout, bns, N, C);
        bn_res_act<<<((size_t)N * C) / 256, 256, 0, stream>>>(
            gout, hwres, S, logC[l], bns, 1.0 / (double)N, g_[l], be_[l],
            l == 2 ? h2 : nullptr, outh[l], outl[l], N * C);
    }

    // JK: P1 -> tB; P0 gemm with fused jk_max(tB, h2) epilogue -> sB split
    gemmM(sAhi, sAlo, P1h, P1l, nullptr, tB, nullptr, nullptr,
          nullptr, nullptr, nullptr, nullptr, N, 64, 256, 0);
    gemmM(sChi, sClo, P0h, P0l, nullptr, nullptr, sBhi, sBlo,
          tB, h2, nullptr, nullptr, N, 64, 256, 0);

    // qkv GEMM with fused kmax epilogue (cols 64..127 = k)
    gemmM(sBhi, sBlo, Gqh, Gql, nullptr, zqkv, nullptr, nullptr,
          nullptr, nullptr, kmaxu, kb, N, 192, 64, 0);

    int ptot = 2 * N + 2 * (N >> 4) * 64;
    qkv_prep<<<(ptot + 255) / 256, 256, 0, stream>>>(
        zqkv, qb, kb, vb, kmaxu, Qb, Kb, Vf, boundArr, N);
    attn_mfma<<<dim3(NCHUNK, (2 * N / 32) / 4), 256, 0, stream>>>(
        Qb, Kb, Vf, boundArr, pl, pacc, N, NCHUNK, N / NCHUNK);
    attn_combine<<<(2 * N * 32 + 255) / 256, 256, 0, stream>>>(
        pl, pacc, sAhi, sAlo, N, NCHUNK);

    // ow + MLP head (split ping-pong sA -> sB -> sA -> sB)
    gemmM(sAhi, sAlo, Owh, Owl, ob, tA, sBhi, sBlo,
          nullptr, nullptr, nullptr, nullptr, N, 64, 64, 0);
    gemmM(sBhi, sBlo, M1h, M1l, m1b, nullptr, sAhi, sAlo,
          nullptr, nullptr, nullptr, nullptr, N, 64, 64, 1);
    gemmM(sAhi, sAlo, M2h, M2l, m2b, nullptr, sBhi, sBlo,
          nullptr, nullptr, nullptr, nullptr, N, 32, 64, 1);
    gemmM(sBhi, sBlo, M3h, M3l, m3b, (float*)d_out, nullptr, nullptr,
          nullptr, nullptr, nullptr, nullptr, N, 10, 32, 0);
}

// Round 13
// 390.565 us; speedup vs baseline: 1.0462x; 1.0462x over previous
//
#include <hip/hip_runtime.h>
#include <hip/hip_bf16.h>

// NeuronGAT forward. Round 12 = r8 (best, 391.7us) + shuffle-free PV only.
//  - r8 base: cvt_pk packing, exp2-domain softmax, float4-per-lane gather,
//    separate bn_finalize/kmax/qk_prep/v_prep/jk_max, attn_combine + 4 gemms,
//    NCHUNK=8.
//  - only change: V rows pre-permuted by sigma(hi,j) in v_prep so P's packed
//    C-layout registers feed the PV B-frag directly (verified r9: absmax
//    unchanged). Removes 8 ds_bpermute + 8 cndmask per 32-key iter.

#define NEG 0.2f
#define LOG2E 1.4426950408889634f

__device__ __forceinline__ float leaky(float v) { return v > 0.f ? v : NEG * v; }

__device__ __forceinline__ unsigned bf16u(float x) {
    unsigned u = __float_as_uint(x);
    u += 0x7FFFu + ((u >> 16) & 1u);
    return u >> 16;
}
__device__ __forceinline__ unsigned fmap(float f) {
    unsigned u = __float_as_uint(f);
    return (u & 0x80000000u) ? ~u : (u | 0x80000000u);
}
__device__ __forceinline__ float funmap(unsigned u) {
    unsigned b = (u & 0x80000000u) ? (u & 0x7FFFFFFFu) : ~u;
    return __uint_as_float(b);
}
__device__ __forceinline__ float fexp2(float x) {
#if __has_builtin(__builtin_amdgcn_exp2f)
    return __builtin_amdgcn_exp2f(x);
#else
    return exp2f(x);
#endif
}
__device__ __forceinline__ unsigned cvtpk(float lo, float hi) {
    unsigned r;
    asm("v_cvt_pk_bf16_f32 %0, %1, %2" : "=v"(r) : "v"(lo), "v"(hi));
    return r;
}

typedef __attribute__((ext_vector_type(8))) short bf16x8;
typedef __attribute__((ext_vector_type(16))) float f32x16;
typedef __attribute__((ext_vector_type(4))) unsigned uint4v;

__device__ __forceinline__ void split1(float v, unsigned& hb, unsigned& lb) {
    hb = bf16u(v);
    float hf = __uint_as_float(hb << 16);
    lb = bf16u(v - hf);
}

__global__ void split_rows(const float* __restrict__ in,
                           unsigned short* __restrict__ hi,
                           unsigned short* __restrict__ lo, int total4)
{
    int i = blockIdx.x * 256 + threadIdx.x;
    if (i >= total4) return;
    float4 v = ((const float4*)in)[i];
    float vv[4] = {v.x, v.y, v.z, v.w};
    ushort4 h, l;
#pragma unroll
    for (int j = 0; j < 4; ++j) {
        unsigned hb, lb;
        split1(vv[j], hb, lb);
        (&h.x)[j] = (unsigned short)hb;
        (&l.x)[j] = (unsigned short)lb;
    }
    ((ushort4*)hi)[i] = h;
    ((ushort4*)lo)[i] = l;
}

struct WEnt { const float* src; unsigned short* hi; unsigned short* lo; int K; int N; };
struct WArr { WEnt e[15]; };

__global__ void split_weights(WArr a)
{
    WEnt w = a.e[blockIdx.y];
    int id = blockIdx.x * 256 + threadIdx.x;
    if (id >= w.K * w.N) return;
    int k = id / w.N, n = id - k * w.N;
    unsigned hb, lb;
    split1(w.src[id], hb, lb);
    w.hi[(size_t)n * w.K + k] = (unsigned short)hb;
    w.lo[(size_t)n * w.K + k] = (unsigned short)lb;
}

// ------------------------------------------------- MFMA split-bf16 GEMM (r6)
__global__ __launch_bounds__(256) void gemm_mfma(
    const unsigned short* __restrict__ Ahi, const unsigned short* __restrict__ Alo,
    const unsigned short* __restrict__ Bhi, const unsigned short* __restrict__ Blo,
    const float* __restrict__ bias, float* __restrict__ C,
    unsigned short* __restrict__ Chi, unsigned short* __restrict__ Clo,
    int M, int N, int K, int act)
{
    const int lane = threadIdx.x & 63, wid = threadIdx.x >> 6;
    const int hb4 = lane >> 5, lq = lane & 31;
    const int row0 = blockIdx.y * 64 + (wid >> 1) * 32;
    const int col0 = blockIdx.x * 64 + (wid & 1) * 32;
    const size_t abase = (size_t)(row0 + lq) * K + hb4 * 8;
    const size_t bbase = (size_t)(col0 + lq) * K + hb4 * 8;
    f32x16 acc0, acc1;
#pragma unroll
    for (int r = 0; r < 16; ++r) { acc0[r] = 0.f; acc1[r] = 0.f; }
    for (int k0 = 0; k0 < K; k0 += 16) {
        bf16x8 a_h = *(const bf16x8*)(Ahi + abase + k0);
        bf16x8 a_l = *(const bf16x8*)(Alo + abase + k0);
        bf16x8 b_h = *(const bf16x8*)(Bhi + bbase + k0);
        bf16x8 b_l = *(const bf16x8*)(Blo + bbase + k0);
        acc0 = __builtin_amdgcn_mfma_f32_32x32x16_bf16(a_h, b_h, acc0, 0, 0, 0);
        acc1 = __builtin_amdgcn_mfma_f32_32x32x16_bf16(a_l, b_h, acc1, 0, 0, 0);
        acc1 = __builtin_amdgcn_mfma_f32_32x32x16_bf16(a_h, b_l, acc1, 0, 0, 0);
    }
    int col = col0 + lq;
    if (col >= N) return;
    float bs = bias ? bias[col] : 0.f;
#pragma unroll
    for (int r = 0; r < 16; ++r) {
        int row = row0 + (r & 3) + 8 * (r >> 2) + 4 * hb4;
        float v = acc0[r] + acc1[r] + bs;
        if (act) v = leaky(v);
        if (C) C[(size_t)row * N + col] = v;
        if (Chi) {
            unsigned hh, ll;
            split1(v, hh, ll);
            Chi[(size_t)row * N + col] = (unsigned short)hh;
            Clo[(size_t)row * N + col] = (unsigned short)ll;
        }
    }
}

// ---------------------------------- GAT scores (x log2e) + global head max
template <int H>
__global__ __launch_bounds__(256) void sd_kernel(
    const float* __restrict__ hwres, int S,
    const float* __restrict__ a_s, const float* __restrict__ a_d,
    float* __restrict__ sval, float* __restrict__ dval,
    unsigned* __restrict__ svmax, int Nn)
{
    int i = blockIdx.x * 256 + threadIdx.x;
    int n = i / H, h = i & (H - 1);
    const float4* row = (const float4*)(hwres + (size_t)n * S + h * 64);
    const float4* as4 = (const float4*)(a_s + h * 64);
    const float4* ad4 = (const float4*)(a_d + h * 64);
    float s = 0.f, d = 0.f;
#pragma unroll
    for (int c = 0; c < 16; ++c) {
        float4 x = row[c], a = as4[c], b = ad4[c];
        s += x.x * a.x + x.y * a.y + x.z * a.z + x.w * a.w;
        d += x.x * b.x + x.y * b.y + x.z * b.z + x.w * b.w;
    }
    s *= LOG2E;
    d *= LOG2E;
    sval[i] = s;
    dval[i] = d;
    float m = s;
#pragma unroll
    for (int off = H; off < 64; off <<= 1) m = fmaxf(m, __shfl_xor(m, off));
    if ((threadIdx.x & 63) < H) atomicMax(&svmax[h], fmap(m));
}

// ------------------------------------------------- CSR build (by dst)
__global__ void csr_count(const int* __restrict__ ei, int* __restrict__ cnt, int E) {
    int i = blockIdx.x * 256 + threadIdx.x;
    if (i < E) atomicAdd(&cnt[ei[E + i]], 1);
}

__global__ __launch_bounds__(256) void csr_scan(const int* __restrict__ cnt,
                                                int* __restrict__ rowptr,
                                                int* __restrict__ fill, int Nn)
{
    __shared__ int part[256];
    int t = threadIdx.x;
    int loc[32];
    int s = 0;
#pragma unroll
    for (int j = 0; j < 32; ++j) { loc[j] = s; s += cnt[t * 32 + j]; }
    part[t] = s;
    __syncthreads();
    for (int d = 1; d < 256; d <<= 1) {
        int v = (t >= d) ? part[t - d] : 0;
        __syncthreads();
        part[t] += v;
        __syncthreads();
    }
    int off = (t > 0) ? part[t - 1] : 0;
#pragma unroll
    for (int j = 0; j < 32; ++j) {
        int v = off + loc[j];
        rowptr[t * 32 + j] = v;
        fill[t * 32 + j] = v;
    }
    if (t == 255) rowptr[Nn] = part[255];
}

__global__ void csr_scatter(const int* __restrict__ ei, int* __restrict__ fill,
                            int* __restrict__ srcidx, int E) {
    int i = blockIdx.x * 256 + threadIdx.x;
    if (i < E) {
        int d = ei[E + i];
        int p = atomicAdd(&fill[d], 1);
        srcidx[p] = ei[i];
    }
}

// ------------------- single-pass GAT gather (fixed-bound, exp2 domain)
__global__ __launch_bounds__(256) void gat_gather4(
    const int* __restrict__ rowptr, const int* __restrict__ srcidx,
    const float* __restrict__ hwres, int S,
    const float* __restrict__ sval, const float* __restrict__ dval,
    const unsigned* __restrict__ svmax, float* __restrict__ gout, int Nn)
{
    const int node = blockIdx.x * 4 + (threadIdx.x >> 6);
    const int lane = threadIdx.x & 63;
    const int hd = lane >> 4;
    const int cb = lane * 4;
    const int beg = rowptr[node], end = rowptr[node + 1];
    const float dv = dval[node * 4 + hd];
    const float B = leaky(funmap(svmax[hd]) + dv);
    float p = fexp2(leaky(sval[node * 4 + hd] + dv) - B);   // self-loop
    float l = p;
    float4 hv = *(const float4*)(hwres + (size_t)node * S + cb);
    float a0 = p * hv.x, a1 = p * hv.y, a2 = p * hv.z, a3 = p * hv.w;
    int i = beg;
    for (; i + 2 <= end; i += 2) {
        int s0 = srcidx[i], s1 = srcidx[i + 1];
        float p0 = fexp2(leaky(sval[s0 * 4 + hd] + dv) - B);
        float p1 = fexp2(leaky(sval[s1 * 4 + hd] + dv) - B);
        float4 r0 = *(const float4*)(hwres + (size_t)s0 * S + cb);
        float4 r1 = *(const float4*)(hwres + (size_t)s1 * S + cb);
        l += p0 + p1;
        a0 += p0 * r0.x + p1 * r1.x;
        a1 += p0 * r0.y + p1 * r1.y;
        a2 += p0 * r0.z + p1 * r1.z;
        a3 += p0 * r0.w + p1 * r1.w;
    }
    if (i < end) {
        int s0 = srcidx[i];
        float p0 = fexp2(leaky(sval[s0 * 4 + hd] + dv) - B);
        float4 r0 = *(const float4*)(hwres + (size_t)s0 * S + cb);
        l += p0;
        a0 += p0 * r0.x; a1 += p0 * r0.y; a2 += p0 * r0.z; a3 += p0 * r0.w;
    }
    float inv = 1.f / l;
    *(float4*)(gout + (size_t)node * 256 + cb) =
        make_float4(a0 * inv, a1 * inv, a2 * inv, a3 * inv);
}

__global__ __launch_bounds__(256) void gat_gather1(
    const int* __restrict__ rowptr, const int* __restrict__ srcidx,
    const float* __restrict__ hwres, int S,
    const float* __restrict__ sval, const float* __restrict__ dval,
    const unsigned* __restrict__ svmax, float* __restrict__ gout, int Nn)
{
    const int node = blockIdx.x * 4 + (threadIdx.x >> 6);
    const int lane = threadIdx.x & 63;
    const int beg = rowptr[node], end = rowptr[node + 1];
    const float dv = dval[node];
    const float B = leaky(funmap(svmax[0]) + dv);
    float p = fexp2(leaky(sval[node] + dv) - B);
    float l = p;
    float acc = p * hwres[(size_t)node * S + lane];
    int i = beg;
    for (; i + 2 <= end; i += 2) {
        int s0 = srcidx[i], s1 = srcidx[i + 1];
        float p0 = fexp2(leaky(sval[s0] + dv) - B);
        float p1 = fexp2(leaky(sval[s1] + dv) - B);
        l += p0 + p1;
        acc += p0 * hwres[(size_t)s0 * S + lane] + p1 * hwres[(size_t)s1 * S + lane];
    }
    if (i < end) {
        int s0 = srcidx[i];
        float p0 = fexp2(leaky(sval[s0] + dv) - B);
        l += p0;
        acc += p0 * hwres[(size_t)s0 * S + lane];
    }
    gout[(size_t)node * 64 + lane] = acc / l;
}

// ------------------------------------------------- BatchNorm (batch stats)
__global__ void bn_partial(const float* __restrict__ gout, double* __restrict__ sums,
                           int Nn, int C)
{
    int t = threadIdx.x;
    int c = t % C, sub = t / C, nsub = blockDim.x / C;
    int rbase = blockIdx.x * 32;
    double s = 0.0, sq = 0.0;
    for (int r = rbase + sub; r < rbase + 32; r += nsub) {
        float x = gout[(size_t)r * C + c];
        s += x;
        sq += (double)x * x;
    }
    atomicAdd(&sums[c], s);
    atomicAdd(&sums[C + c], sq);
}

__global__ void bn_finalize(const double* __restrict__ sums, float* __restrict__ mu,
                            float* __restrict__ rstd, int Nn, int C)
{
    int c = threadIdx.x;
    if (c >= C) return;
    double m = sums[c] / Nn;
    double v = sums[C + c] / Nn - m * m;
    mu[c] = (float)m;
    rstd[c] = (float)(1.0 / sqrt(v + 1e-5));
}

__global__ void bn_res_act(const float* __restrict__ gout,
                           const float* __restrict__ hwres, int S, int logC,
                           const float* __restrict__ mu, const float* __restrict__ rstd,
                           const float* __restrict__ g, const float* __restrict__ be,
                           float* __restrict__ outp,
                           unsigned short* __restrict__ shi,
                           unsigned short* __restrict__ slo, int total)
{
    int i = blockIdx.x * blockDim.x + threadIdx.x;
    if (i >= total) return;
    int C = 1 << logC;
    int c = i & (C - 1), row = i >> logC;
    float v = (gout[i] - mu[c]) * rstd[c] * g[c] + be[c]
              + hwres[(size_t)row * S + C + c];
    v = leaky(v);
    if (outp) outp[i] = v;
    if (shi) {
        unsigned hb, lb;
        split1(v, hb, lb);
        shi[i] = (unsigned short)hb;
        slo[i] = (unsigned short)lb;
    }
}

__global__ void jk_max(const float* __restrict__ a, const float* __restrict__ b,
                       const float* __restrict__ c,
                       unsigned short* __restrict__ shi,
                       unsigned short* __restrict__ slo, int total)
{
    int i = blockIdx.x * blockDim.x + threadIdx.x;
    if (i >= total) return;
    float v = fmaxf(fmaxf(a[i], b[i]), c[i]);
    unsigned hb, lb;
    split1(v, hb, lb);
    shi[i] = (unsigned short)hb;
    slo[i] = (unsigned short)lb;
}

// ------------------------------------------------- per-dim |k| max (biased k)
__global__ void kmax_kernel(const float* __restrict__ zqkv,
                            const float* __restrict__ kb,
                            unsigned* __restrict__ kmax, int N)
{
    const int c = threadIdx.x & 63, g = threadIdx.x >> 6;
    const int rows = N / (gridDim.x * 4);
    const int r0 = (blockIdx.x * 4 + g) * rows;
    float bc = kb[c];
    float m = 0.f;
    for (int r = r0; r < r0 + rows; ++r)
        m = fmaxf(m, fabsf(zqkv[(size_t)r * 192 + 64 + c] + bc));
    atomicMax(&kmax[c], __float_as_uint(m));
}

// -------------------------- attn prep: Q scaled by scale*log2e (exp2 domain)
__global__ void qk_prep(const float* __restrict__ zqkv,
                        const float* __restrict__ qb, const float* __restrict__ kb,
                        const unsigned* __restrict__ kmaxu,
                        __hip_bfloat16* __restrict__ Qb, __hip_bfloat16* __restrict__ Kb,
                        float* __restrict__ bound, int N)
{
    int idx = blockIdx.x * 256 + threadIdx.x;
    if (idx >= 2 * N) return;
    int h = idx / N, row = idx - h * N;
    const float scale = 0.17677669529663687f * LOG2E;
    const float* qp = zqkv + (size_t)row * 192 + h * 32;
    const float* kp = zqkv + (size_t)row * 192 + 64 + h * 32;
    float b = 0.f;
    unsigned qo[16], ko[16];
#pragma unroll
    for (int i = 0; i < 16; ++i) {
        float q0 = (qp[2 * i] + qb[h * 32 + 2 * i]) * scale;
        float q1 = (qp[2 * i + 1] + qb[h * 32 + 2 * i + 1]) * scale;
        float k0 = kp[2 * i] + kb[h * 32 + 2 * i];
        float k1 = kp[2 * i + 1] + kb[h * 32 + 2 * i + 1];
        b += fabsf(q0) * __uint_as_float(kmaxu[h * 32 + 2 * i]);
        b += fabsf(q1) * __uint_as_float(kmaxu[h * 32 + 2 * i + 1]);
        qo[i] = bf16u(q0) | (bf16u(q1) << 16);
        ko[i] = bf16u(k0) | (bf16u(k1) << 16);
    }
    uint4* qd = (uint4*)(Qb + (size_t)idx * 32);
    uint4* kd = (uint4*)(Kb + (size_t)idx * 32);
#pragma unroll
    for (int i = 0; i < 4; ++i) {
        qd[i] = make_uint4(qo[4 * i], qo[4 * i + 1], qo[4 * i + 2], qo[4 * i + 3]);
        kd[i] = make_uint4(ko[4 * i], ko[4 * i + 1], ko[4 * i + 2], ko[4 * i + 3]);
    }
    bound[idx] = b;
}

// V in sigma-permuted PV A-frag layout: slot pair (2i,2i+1) of lane group hi
// holds V rows kbase + ((2i)&3) + 8*(i>>1) {, +1} where kbase = g*16 + 4*hi.
// This matches the MFMA C-layout order of P so PV needs no lane exchange.
__global__ void v_prep(const float* __restrict__ zqkv, const float* __restrict__ vb,
                       __hip_bfloat16* __restrict__ Vf, int N)
{
    int idx = blockIdx.x * 256 + threadIdx.x;
    int total = 2 * (N >> 4) * 64;
    if (idx >= total) return;
    int lane = idx & 63;
    int g = (idx >> 6) % (N >> 4);
    int h = (idx >> 6) / (N >> 4);
    int hi = lane >> 5;
    int kbase = g * 16 + 4 * hi;
    int d = (lane & 31) + h * 32;
    float bd = vb[d];
    unsigned o[4];
#pragma unroll
    for (int i = 0; i < 4; ++i) {
        int r0 = kbase + ((2 * i) & 3) + 8 * (i >> 1);
        unsigned u0 = bf16u(zqkv[(size_t)r0 * 192 + 128 + d] + bd);
        unsigned u1 = bf16u(zqkv[(size_t)(r0 + 1) * 192 + 128 + d] + bd);
        o[i] = u0 | (u1 << 16);
    }
    *(uint4*)(Vf + (size_t)idx * 8) = make_uint4(o[0], o[1], o[2], o[3]);
}

// ------------------------------------------------- MFMA self-attention
// sigma-permuted V => P's packed registers feed the PV B-frag directly.
__global__ __launch_bounds__(256) void attn_mfma(
    const __hip_bfloat16* __restrict__ Qb, const __hip_bfloat16* __restrict__ Kb,
    const __hip_bfloat16* __restrict__ Vf, const float* __restrict__ bound,
    float* __restrict__ pl, __hip_bfloat16* __restrict__ pacc,
    int N, int nchunk, int chunksz)
{
    const int lane = threadIdx.x & 63;
    const int wid = threadIdx.x >> 6;
    const int hi = lane >> 5, lq = lane & 31;
    const int chunk = blockIdx.x;
    const int qtile = blockIdx.y * 4 + wid;
    const int head = qtile / (N >> 5);
    const int q0 = (qtile % (N >> 5)) * 32;
    const int kbase = chunk * chunksz;

    const size_t qrow = (size_t)head * N + q0 + lq;
    const bf16x8 qf0 = *(const bf16x8*)(Qb + qrow * 32 + hi * 8);
    const bf16x8 qf1 = *(const bf16x8*)(Qb + qrow * 32 + hi * 8 + 16);
    const float bnd = bound[qrow];

    f32x16 oacc;
#pragma unroll
    for (int r = 0; r < 16; ++r) oacc[r] = 0.f;
    float lsum = 0.f;

    for (int kt = kbase; kt < kbase + chunksz; kt += 32) {
        const size_t krow = (size_t)head * N + kt + lq;
        const bf16x8 kf0 = *(const bf16x8*)(Kb + krow * 32 + hi * 8);
        const bf16x8 kf1 = *(const bf16x8*)(Kb + krow * 32 + hi * 8 + 16);
        f32x16 s;
#pragma unroll
        for (int r = 0; r < 16; ++r) s[r] = 0.f;
        s = __builtin_amdgcn_mfma_f32_32x32x16_bf16(kf0, qf0, s, 0, 0, 0);
        s = __builtin_amdgcn_mfma_f32_32x32x16_bf16(kf1, qf1, s, 0, 0, 0);
        const __hip_bfloat16* vfb =
            Vf + (((size_t)head * (N >> 4) + (kt >> 4)) * 64 + lane) * 8;
        const bf16x8 vf0 = *(const bf16x8*)vfb;
        const bf16x8 vf1 = *(const bf16x8*)(vfb + 64 * 8);

        float p[16];
#pragma unroll
        for (int r = 0; r < 16; ++r) p[r] = fexp2(s[r] - bnd);
        float ls = 0.f;
#pragma unroll
        for (int r = 0; r < 16; ++r) ls += p[r];
        lsum += ls;

        uint4v b1, b2;
        b1[0] = cvtpk(p[0], p[1]);
        b1[1] = cvtpk(p[2], p[3]);
        b1[2] = cvtpk(p[4], p[5]);
        b1[3] = cvtpk(p[6], p[7]);
        b2[0] = cvtpk(p[8], p[9]);
        b2[1] = cvtpk(p[10], p[11]);
        b2[2] = cvtpk(p[12], p[13]);
        b2[3] = cvtpk(p[14], p[15]);
        oacc = __builtin_amdgcn_mfma_f32_32x32x16_bf16(
            vf0, __builtin_bit_cast(bf16x8, b1), oacc, 0, 0, 0);
        oacc = __builtin_amdgcn_mfma_f32_32x32x16_bf16(
            vf1, __builtin_bit_cast(bf16x8, b2), oacc, 0, 0, 0);
    }
    lsum += __shfl_xor(lsum, 32);
    const size_t hr = (size_t)head * N + q0 + lq;
    if (hi == 0) pl[hr * nchunk + chunk] = lsum;
    __hip_bfloat16* pb = pacc + (hr * nchunk + chunk) * 32;
#pragma unroll
    for (int rg = 0; rg < 4; ++rg) {
        unsigned lo = cvtpk(oacc[rg * 4 + 0], oacc[rg * 4 + 1]);
        unsigned hw2 = cvtpk(oacc[rg * 4 + 2], oacc[rg * 4 + 3]);
        *(uint2*)(pb + rg * 8 + hi * 4) = make_uint2(lo, hw2);
    }
}

__global__ void attn_combine(const float* __restrict__ pl,
                             const __hip_bfloat16* __restrict__ pacc,
                             unsigned short* __restrict__ shi,
                             unsigned short* __restrict__ slo, int N, int nchunk)
{
    int i = blockIdx.x * blockDim.x + threadIdx.x;
    if (i >= 2 * N * 32) return;
    int hr = i >> 5, cc = i & 31;
    float l = 0.f, a = 0.f;
    for (int c = 0; c < nchunk; ++c) {
        l += pl[(size_t)hr * nchunk + c];
        a += __bfloat162float(pacc[((size_t)hr * nchunk + c) * 32 + cc]);
    }
    int head = hr / N, row = hr - head * N;
    float v = a / l;
    size_t oi = (size_t)row * 64 + head * 32 + cc;
    unsigned hb, lb;
    split1(v, hb, lb);
    shi[oi] = (unsigned short)hb;
    slo[oi] = (unsigned short)lb;
}

// ----------------------------------------------------------------- host
extern "C" void kernel_launch(void* const* d_in, const int* in_sizes, int n_in,
                              void* d_out, int out_size, void* d_ws, size_t ws_size,
                              hipStream_t stream)
{
    const float* x = (const float*)d_in[0];
    const int* ei = (const int*)d_in[1];
    const float* w[3]   = {(const float*)d_in[2], (const float*)d_in[6],  (const float*)d_in[10]};
    const float* as_[3] = {(const float*)d_in[3], (const float*)d_in[7],  (const float*)d_in[11]};
    const float* ad_[3] = {(const float*)d_in[4], (const float*)d_in[8],  (const float*)d_in[12]};
    const float* rw[3]  = {(const float*)d_in[5], (const float*)d_in[9],  (const float*)d_in[13]};
    const float* p0 = (const float*)d_in[14];
    const float* p1 = (const float*)d_in[15];
    const float* qw = (const float*)d_in[16];
    const float* kw = (const float*)d_in[17];
    const float* vw = (const float*)d_in[18];
    const float* ow = (const float*)d_in[19];
    const float* m1w = (const float*)d_in[20];
    const float* m2w = (const float*)d_in[21];
    const float* m3w = (const float*)d_in[22];
    const float* g_[3]  = {(const float*)d_in[23], (const float*)d_in[24], (const float*)d_in[25]};
    const float* be_[3] = {(const float*)d_in[26], (const float*)d_in[27], (const float*)d_in[28]};
    const float* qb  = (const float*)d_in[32];
    const float* kb  = (const float*)d_in[33];
    const float* vb  = (const float*)d_in[34];
    const float* ob  = (const float*)d_in[35];
    const float* m1b = (const float*)d_in[36];
    const float* m2b = (const float*)d_in[37];
    const float* m3b = (const float*)d_in[38];

    const int N = in_sizes[0] / 64; // 8192
    const int E = in_sizes[1] / 2;  // 262144

    float* ws = (float*)d_ws;
    size_t off = 0;
    auto alloc = [&](size_t n) {
        float* p = ws + off;
        off += (n + 255) & ~(size_t)255;
        return p;
    };
    float* hwres = alloc((size_t)N * 512);
    float* gout  = alloc((size_t)N * 256);
    unsigned short* sChi = (unsigned short*)alloc((size_t)N * 128);
    unsigned short* sClo = (unsigned short*)alloc((size_t)N * 128);
    float* h2   = alloc((size_t)N * 64);
    float* sval = alloc((size_t)N * 4);
    float* dval = alloc((size_t)N * 4);
    float* mu   = alloc(256);
    float* rstd = alloc(256);
    size_t ms_begin = off;
    int* cnt = (int*)alloc(N);
    double* bnsum = (double*)alloc(3 * 1024);
    unsigned* kmaxu = (unsigned*)alloc(64);
    unsigned* svmax = (unsigned*)alloc(16);
    size_t ms_end = off;
    int* rowptr = (int*)alloc(N + 256);
    int* fill   = (int*)alloc(N);
    int* srcidx = (int*)alloc(E);
    unsigned short* sAhi = (unsigned short*)alloc((size_t)N * 128);
    unsigned short* sAlo = (unsigned short*)alloc((size_t)N * 128);
    unsigned short* sBhi = (unsigned short*)alloc((size_t)N * 32);
    unsigned short* sBlo = (unsigned short*)alloc((size_t)N * 32);
    unsigned short* G0h = (unsigned short*)alloc(512 * 64 / 2);
    unsigned short* G0l = (unsigned short*)alloc(512 * 64 / 2);
    unsigned short* G1h = (unsigned short*)alloc(512 * 256 / 2);
    unsigned short* G1l = (unsigned short*)alloc(512 * 256 / 2);
    unsigned short* G2h = (unsigned short*)alloc(128 * 256 / 2);
    unsigned short* G2l = (unsigned short*)alloc(128 * 256 / 2);
    unsigned short* P0h = (unsigned short*)alloc(64 * 256 / 2);
    unsigned short* P0l = (unsigned short*)alloc(64 * 256 / 2);
    unsigned short* P1h = (unsigned short*)alloc(64 * 256 / 2);
    unsigned short* P1l = (unsigned short*)alloc(64 * 256 / 2);
    unsigned short* Gqh = (unsigned short*)alloc(192 * 64 / 2);
    unsigned short* Gql = (unsigned short*)alloc(192 * 64 / 2);
    unsigned short* Owh = (unsigned short*)alloc(64 * 64 / 2);
    unsigned short* Owl = (unsigned short*)alloc(64 * 64 / 2);
    unsigned short* M1h = (unsigned short*)alloc(64 * 64 / 2);
    unsigned short* M1l = (unsigned short*)alloc(64 * 64 / 2);
    unsigned short* M2h = (unsigned short*)alloc(64 * 64 / 2);
    unsigned short* M2l = (unsigned short*)alloc(64 * 64 / 2);
    unsigned short* M3h = (unsigned short*)alloc(64 * 32 / 2);
    unsigned short* M3l = (unsigned short*)alloc(64 * 32 / 2);
    float* zqkv = hwres;
    __hip_bfloat16* pacc = (__hip_bfloat16*)(hwres + (size_t)N * 192);
    float* tA = gout;
    float* tB = gout + (size_t)N * 64;
    float* tC = gout + 2 * (size_t)N * 64;
    const int NCHUNK = 8;
    __hip_bfloat16* Qb = (__hip_bfloat16*)sChi;
    __hip_bfloat16* Kb = Qb + (size_t)2 * N * 32;
    __hip_bfloat16* Vf = Kb + (size_t)2 * N * 32;
    float* boundArr = (float*)(Vf + (size_t)2 * N * 32);
    float* pl = h2;

    {
        WArr wa;
        wa.e[0]  = WEnt{w[0],  G0h,              G0l,              64, 256};
        wa.e[1]  = WEnt{rw[0], G0h + 256 * 64,   G0l + 256 * 64,   64, 256};
        wa.e[2]  = WEnt{w[1],  G1h,              G1l,              256, 256};
        wa.e[3]  = WEnt{rw[1], G1h + 256 * 256,  G1l + 256 * 256,  256, 256};
        wa.e[4]  = WEnt{w[2],  G2h,              G2l,              256, 64};
        wa.e[5]  = WEnt{rw[2], G2h + 64 * 256,   G2l + 64 * 256,   256, 64};
        wa.e[6]  = WEnt{p0,    P0h,              P0l,              256, 64};
        wa.e[7]  = WEnt{p1,    P1h,              P1l,              256, 64};
        wa.e[8]  = WEnt{qw,    Gqh,              Gql,              64, 64};
        wa.e[9]  = WEnt{kw,    Gqh + 64 * 64,    Gql + 64 * 64,    64, 64};
        wa.e[10] = WEnt{vw,    Gqh + 128 * 64,   Gql + 128 * 64,   64, 64};
        wa.e[11] = WEnt{ow,    Owh,              Owl,              64, 64};
        wa.e[12] = WEnt{m1w,   M1h,              M1l,              64, 64};
        wa.e[13] = WEnt{m2w,   M2h,              M2l,              64, 32};
        wa.e[14] = WEnt{m3w,   M3h,              M3l,              32, 10};
        split_weights<<<dim3(256, 15), 256, 0, stream>>>(wa);
    }
    hipMemsetAsync(ws + ms_begin, 0, (ms_end - ms_begin) * 4, stream);
    csr_count<<<(E + 255) / 256, 256, 0, stream>>>(ei, cnt, E);
    csr_scan<<<1, 256, 0, stream>>>(cnt, rowptr, fill, N);
    csr_scatter<<<(E + 255) / 256, 256, 0, stream>>>(ei, fill, srcidx, E);
    split_rows<<<(N * 64 / 4 + 255) / 256, 256, 0, stream>>>(x, sAhi, sAlo, N * 64 / 4);

    auto gemmM = [&](const unsigned short* Ah, const unsigned short* Al,
                     const unsigned short* Bh, const unsigned short* Bl,
                     const float* bias, float* C, unsigned short* Chi,
                     unsigned short* Clo, int M, int Nc, int K, int act) {
        dim3 grid((Nc + 63) / 64, M / 64);
        gemm_mfma<<<grid, 256, 0, stream>>>(Ah, Al, Bh, Bl, bias, C, Chi, Clo,
                                            M, Nc, K, act);
    };

    const unsigned short* inh[3] = {sAhi, sChi, sAhi};
    const unsigned short* inl[3] = {sAlo, sClo, sAlo};
    unsigned short* outh[3] = {sChi, sAhi, nullptr};
    unsigned short* outl[3] = {sClo, sAlo, nullptr};
    const unsigned short* Gh[3] = {G0h, G1h, G2h};
    const unsigned short* Gl[3] = {G0l, G1l, G2l};
    int Ksz[3] = {64, 256, 256}, Csz[3] = {256, 256, 64}, logC[3] = {8, 8, 6};
    int Hh[3] = {4, 4, 1};

    for (int l = 0; l < 3; ++l) {
        int C = Csz[l], S = 2 * C;
        gemmM(inh[l], inl[l], Gh[l], Gl[l], nullptr, hwres, nullptr, nullptr,
              N, S, Ksz[l], 0);
        if (Hh[l] == 4) {
            sd_kernel<4><<<N * 4 / 256, 256, 0, stream>>>(
                hwres, S, as_[l], ad_[l], sval, dval, svmax + l * 4, N);
            gat_gather4<<<N / 4, 256, 0, stream>>>(
                rowptr, srcidx, hwres, S, sval, dval, svmax + l * 4, gout, N);
        } else {
            sd_kernel<1><<<N / 256, 256, 0, stream>>>(
                hwres, S, as_[l], ad_[l], sval, dval, svmax + l * 4, N);
            gat_gather1<<<N / 4, 256, 0, stream>>>(
                rowptr, srcidx, hwres, S, sval, dval, svmax + l * 4, gout, N);
        }
        double* bns = bnsum + l * 512;
        bn_partial<<<N / 32, 256, 0, stream>>>(gout, bns, N, C);
        bn_finalize<<<1, 256, 0, stream>>>(bns, mu, rstd, N, C);
        bn_res_act<<<((size_t)N * C) / 256, 256, 0, stream>>>(
            gout, hwres, S, logC[l], mu, rstd, g_[l], be_[l],
            l == 2 ? h2 : nullptr, outh[l], outl[l], N * C);
    }

    gemmM(sChi, sClo, P0h, P0l, nullptr, tA, nullptr, nullptr, N, 64, 256, 0);
    gemmM(sAhi, sAlo, P1h, P1l, nullptr, tB, nullptr, nullptr, N, 64, 256, 0);
    jk_max<<<((size_t)N * 64) / 256, 256, 0, stream>>>(tA, tB, h2, sBhi, sBlo, N * 64);

    gemmM(sBhi, sBlo, Gqh, Gql, nullptr, zqkv, nullptr, nullptr, N, 192, 64, 0);

    kmax_kernel<<<32, 256, 0, stream>>>(zqkv, kb, kmaxu, N);
    qk_prep<<<(2 * N + 255) / 256, 256, 0, stream>>>(zqkv, qb, kb, kmaxu, Qb, Kb, boundArr, N);
    v_prep<<<(2 * (N >> 4) * 64 + 255) / 256, 256, 0, stream>>>(zqkv, vb, Vf, N);
    attn_mfma<<<dim3(NCHUNK, (2 * N / 32) / 4), 256, 0, stream>>>(
        Qb, Kb, Vf, boundArr, pl, pacc, N, NCHUNK, N / NCHUNK);
    attn_combine<<<(2 * N * 32 + 255) / 256, 256, 0, stream>>>(
        pl, pacc, sAhi, sAlo, N, NCHUNK);

    gemmM(sAhi, sAlo, Owh, Owl, ob, tA, sBhi, sBlo, N, 64, 64, 0);
    gemmM(sBhi, sBlo, M1h, M1l, m1b, nullptr, sAhi, sAlo, N, 64, 64, 1);
    gemmM(sAhi, sAlo, M2h, M2l, m2b, nullptr, sBhi, sBlo, N, 32, 64, 1);
    gemmM(sBhi, sBlo, M3h, M3l, m3b, (float*)d_out, nullptr, nullptr, N, 10, 32, 0);
}